// Round 1
// baseline (322.855 us; speedup 1.0000x reference)
//
#include <hip/hip_runtime.h>
#include <hip/hip_bf16.h>

#define BS 2
#define SEQ 2048
#define DIN 1024
#define HID 1024
#define NH 16
#define HD 64
#define M_ROWS (BS*SEQ)

typedef __attribute__((ext_vector_type(8))) short short8;
typedef __attribute__((ext_vector_type(8))) __bf16 bf16x8;
typedef __attribute__((ext_vector_type(4))) float floatx4;

__device__ __forceinline__ short f2bf(float f) {
  unsigned u = __float_as_uint(f);
  u += 0x7fffu + ((u >> 16) & 1u);
  return (short)(u >> 16);
}

__device__ __forceinline__ floatx4 mfma16(short8 a, short8 b, floatx4 c) {
  return __builtin_amdgcn_mfma_f32_16x16x32_bf16(
      __builtin_bit_cast(bf16x8, a), __builtin_bit_cast(bf16x8, b), c, 0, 0, 0);
}

// C[M][N] = A[M][K] @ B[K][N] + bias[N]
// A: fp32 (A_F32) or bf16-bits (short). C: fp32 (OUT_F32) or bf16-bits.
template<bool A_F32, bool OUT_F32>
__global__ __launch_bounds__(256) void gemm_bias_kernel(
    const void* __restrict__ Ap, const float* __restrict__ B,
    const float* __restrict__ bias, void* __restrict__ Cp,
    int Mdim, int Ndim, int Kdim)
{
  __shared__ short As[128][40];   // [m][k], padded
  __shared__ short Bst[64][40];   // [n][k], padded (B transposed)
  const int tid = threadIdx.x;
  const int m0 = blockIdx.y * 128, n0 = blockIdx.x * 64;
  const int wid = tid >> 6, lane = tid & 63;
  const int lg = lane >> 4, lm = lane & 15;
  const int wr = wid >> 1, wc = wid & 1;   // wave tile: 64 rows x 32 cols
  const float* Af = (const float*)Ap;
  const short* Ab = (const short*)Ap;

  floatx4 acc[4][2];
  #pragma unroll
  for (int i = 0; i < 4; ++i)
    #pragma unroll
    for (int j = 0; j < 2; ++j) acc[i][j] = floatx4{0.f, 0.f, 0.f, 0.f};

  for (int k0 = 0; k0 < Kdim; k0 += 32) {
    __syncthreads();
    #pragma unroll
    for (int i = 0; i < 16; ++i) {           // A tile: 128x32
      int idx = tid + i * 256;
      int m = idx >> 5, kk = idx & 31;
      short sv;
      if (A_F32) sv = f2bf(Af[(size_t)(m0 + m) * Kdim + k0 + kk]);
      else       sv = Ab[(size_t)(m0 + m) * Kdim + k0 + kk];
      As[m][kk] = sv;
    }
    #pragma unroll
    for (int i = 0; i < 8; ++i) {            // B tile: 32x64, stored transposed
      int idx = tid + i * 256;
      int kk = idx >> 6, n = idx & 63;
      Bst[n][kk] = f2bf(B[(size_t)(k0 + kk) * Ndim + n0 + n]);
    }
    __syncthreads();

    short8 a[4], bfr[2];
    #pragma unroll
    for (int mt = 0; mt < 4; ++mt)
      a[mt] = *(const short8*)&As[wr * 64 + mt * 16 + lm][lg * 8];
    #pragma unroll
    for (int nt = 0; nt < 2; ++nt)
      bfr[nt] = *(const short8*)&Bst[wc * 32 + nt * 16 + lm][lg * 8];
    #pragma unroll
    for (int mt = 0; mt < 4; ++mt)
      #pragma unroll
      for (int nt = 0; nt < 2; ++nt)
        acc[mt][nt] = mfma16(a[mt], bfr[nt], acc[mt][nt]);
  }

  #pragma unroll
  for (int mt = 0; mt < 4; ++mt) {
    #pragma unroll
    for (int nt = 0; nt < 2; ++nt) {
      #pragma unroll
      for (int r = 0; r < 4; ++r) {
        int row = m0 + wr * 64 + mt * 16 + 4 * lg + r;
        int col = n0 + wc * 32 + nt * 16 + lm;
        float v = acc[mt][nt][r] + bias[col];
        if (OUT_F32) ((float*)Cp)[(size_t)row * Ndim + col] = v;
        else         ((short*)Cp)[(size_t)row * Ndim + col] = f2bf(v);
      }
    }
  }
}

// Flash attention: 1 block = (b, h, 64 q-rows); 4 waves x 16 q-rows; KV tile 64.
__global__ __launch_bounds__(256) void attn_kernel(
    const short* __restrict__ q, const short* __restrict__ k,
    const short* __restrict__ v, short* __restrict__ att)
{
  __shared__ short Ks[64][72];       // [kv][d]
  __shared__ short Vt[64][72];       // [d][kv]  (V transposed)
  __shared__ short Ps[4][16][72];    // per-wave P strip [q][kv]
  const int tid = threadIdx.x;
  const int wid = tid >> 6, lane = tid & 63;
  const int lg = lane >> 4, lm = lane & 15;
  const int q0 = blockIdx.x * 64;
  const int bh = blockIdx.y;
  const int b = bh >> 4, h = bh & 15;
  const size_t base = ((size_t)b * SEQ) * HID + (size_t)h * HD;

  // Q fragments for this wave's 16 rows (rows q0+wid*16+lm), contiguous d
  short8 qf[2];
  {
    const short* qrow = q + base + (size_t)(q0 + wid * 16 + lm) * HID;
    #pragma unroll
    for (int kk = 0; kk < 2; ++kk)
      qf[kk] = *(const short8*)(qrow + kk * 32 + lg * 8);
  }

  float mrow[4], lrow[4];
  floatx4 o[4];
  #pragma unroll
  for (int r = 0; r < 4; ++r) { mrow[r] = -3e38f; lrow[r] = 0.f; }
  #pragma unroll
  for (int nt = 0; nt < 4; ++nt) o[nt] = floatx4{0.f, 0.f, 0.f, 0.f};

  const int ntile = blockIdx.x + 1;   // causal: kv tiles 0..q0/64
  for (int t = 0; t < ntile; ++t) {
    const int kv0 = t * 64;
    __syncthreads();   // previous iter's LDS reads done
    #pragma unroll
    for (int i = 0; i < 2; ++i) {     // stage K rows + V transposed
      int idx = tid + i * 256;        // 0..511 : 8-elem chunks of 64x64
      int r = idx >> 3, c8 = (idx & 7) * 8;
      const short8 kv8 = *(const short8*)(k + base + (size_t)(kv0 + r) * HID + c8);
      *(short8*)&Ks[r][c8] = kv8;
      const short8 vv8 = *(const short8*)(v + base + (size_t)(kv0 + r) * HID + c8);
      #pragma unroll
      for (int j = 0; j < 8; ++j) Vt[c8 + j][r] = vv8[j];
    }
    __syncthreads();

    // S strip = Q(16xD) K^T(Dx64)
    floatx4 s[4];
    #pragma unroll
    for (int nt = 0; nt < 4; ++nt) s[nt] = floatx4{0.f, 0.f, 0.f, 0.f};
    #pragma unroll
    for (int kk = 0; kk < 2; ++kk) {
      #pragma unroll
      for (int nt = 0; nt < 4; ++nt) {
        short8 kf = *(const short8*)&Ks[nt * 16 + lm][kk * 32 + lg * 8];
        s[nt] = mfma16(qf[kk], kf, s[nt]);
      }
    }

    // scale + causal mask + online softmax
    float p[4][4], pm[4];
    #pragma unroll
    for (int r = 0; r < 4; ++r) pm[r] = -3e38f;
    #pragma unroll
    for (int nt = 0; nt < 4; ++nt) {
      #pragma unroll
      for (int r = 0; r < 4; ++r) {
        int qrow = q0 + wid * 16 + 4 * lg + r;
        int kcol = kv0 + nt * 16 + lm;
        float val = s[nt][r] * 0.125f;
        if (kcol > qrow) val = -3e38f;
        p[nt][r] = val;
        pm[r] = fmaxf(pm[r], val);
      }
    }
    #pragma unroll
    for (int r = 0; r < 4; ++r) {
      #pragma unroll
      for (int off = 1; off < 16; off <<= 1)
        pm[r] = fmaxf(pm[r], __shfl_xor(pm[r], off));
    }
    float corr[4], psum[4];
    #pragma unroll
    for (int r = 0; r < 4; ++r) {
      float mnew = fmaxf(mrow[r], pm[r]);
      corr[r] = __expf(mrow[r] - mnew);
      mrow[r] = mnew;
      psum[r] = 0.f;
    }
    #pragma unroll
    for (int nt = 0; nt < 4; ++nt) {
      #pragma unroll
      for (int r = 0; r < 4; ++r) {
        float e = __expf(p[nt][r] - mrow[r]);
        p[nt][r] = e;
        psum[r] += e;
      }
    }
    #pragma unroll
    for (int r = 0; r < 4; ++r) {
      #pragma unroll
      for (int off = 1; off < 16; off <<= 1)
        psum[r] += __shfl_xor(psum[r], off);
      lrow[r] = lrow[r] * corr[r] + psum[r];
    }
    #pragma unroll
    for (int nt = 0; nt < 4; ++nt)
      #pragma unroll
      for (int r = 0; r < 4; ++r)
        o[nt][r] *= corr[r];

    // P (C/D layout) -> LDS -> A layout
    #pragma unroll
    for (int nt = 0; nt < 4; ++nt)
      #pragma unroll
      for (int r = 0; r < 4; ++r)
        Ps[wid][4 * lg + r][nt * 16 + lm] = f2bf(p[nt][r]);
    __syncthreads();

    // O += P(16x64) V(64x64)
    #pragma unroll
    for (int kk = 0; kk < 2; ++kk) {
      short8 pf = *(const short8*)&Ps[wid][lm][kk * 32 + lg * 8];
      #pragma unroll
      for (int nt = 0; nt < 4; ++nt) {
        short8 vf = *(const short8*)&Vt[nt * 16 + lm][kk * 32 + lg * 8];
        o[nt] = mfma16(pf, vf, o[nt]);
      }
    }
  }

  // normalize + store att (bf16)
  #pragma unroll
  for (int nt = 0; nt < 4; ++nt) {
    #pragma unroll
    for (int r = 0; r < 4; ++r) {
      int row = q0 + wid * 16 + 4 * lg + r;
      int col = h * HD + nt * 16 + lm;
      float val = o[nt][r] / lrow[r];
      att[((size_t)(b * SEQ + row)) * HID + col] = f2bf(val);
    }
  }
}

extern "C" void kernel_launch(void* const* d_in, const int* in_sizes, int n_in,
                              void* d_out, int out_size, void* d_ws, size_t ws_size,
                              hipStream_t stream) {
  (void)in_sizes; (void)n_in; (void)out_size; (void)ws_size;
  const float* x    = (const float*)d_in[0];
  const float* Wq   = (const float*)d_in[1];
  const float* bq   = (const float*)d_in[2];
  const float* Wk   = (const float*)d_in[3];
  const float* bk   = (const float*)d_in[4];
  const float* Wv   = (const float*)d_in[5];
  const float* bv   = (const float*)d_in[6];
  const float* Wmix = (const float*)d_in[7];
  const float* bmix = (const float*)d_in[8];
  float* out = (float*)d_out;

  short* qb = (short*)d_ws;                       // [M_ROWS][HID] bf16
  short* kb = qb + (size_t)M_ROWS * HID;
  short* vb = kb + (size_t)M_ROWS * HID;
  short* ab = vb + (size_t)M_ROWS * HID;

  dim3 blk(256);
  dim3 gg(HID / 64, M_ROWS / 128);
  hipLaunchKernelGGL((gemm_bias_kernel<true, false>), gg, blk, 0, stream,
                     (const void*)x, Wq, bq, (void*)qb, M_ROWS, HID, DIN);
  hipLaunchKernelGGL((gemm_bias_kernel<true, false>), gg, blk, 0, stream,
                     (const void*)x, Wk, bk, (void*)kb, M_ROWS, HID, DIN);
  hipLaunchKernelGGL((gemm_bias_kernel<true, false>), gg, blk, 0, stream,
                     (const void*)x, Wv, bv, (void*)vb, M_ROWS, HID, DIN);

  dim3 ga(SEQ / 64, BS * NH);
  hipLaunchKernelGGL(attn_kernel, ga, blk, 0, stream, qb, kb, vb, ab);

  hipLaunchKernelGGL((gemm_bias_kernel<false, true>), gg, blk, 0, stream,
                     (const void*)ab, Wmix, bmix, (void*)out, M_ROWS, HID, DIN);
}

// Round 2
// 194.715 us; speedup vs baseline: 1.6581x; 1.6581x over previous
//
#include <hip/hip_runtime.h>
#include <hip/hip_bf16.h>

#define BS 2
#define SEQ 2048
#define DIN 1024
#define HID 1024
#define NH 16
#define HD 64
#define M_ROWS (BS*SEQ)
#define NQKV 3072

typedef __attribute__((ext_vector_type(8))) short short8;
typedef __attribute__((ext_vector_type(4))) short short4v;
typedef __attribute__((ext_vector_type(8))) __bf16 bf16x8;
typedef __attribute__((ext_vector_type(4))) float floatx4;

__device__ __forceinline__ short f2bf(float f) {
  unsigned u = __float_as_uint(f);
  u += 0x7fffu + ((u >> 16) & 1u);
  return (short)(u >> 16);
}

__device__ __forceinline__ floatx4 mfma16(short8 a, short8 b, floatx4 c) {
  return __builtin_amdgcn_mfma_f32_16x16x32_bf16(
      __builtin_bit_cast(bf16x8, a), __builtin_bit_cast(bf16x8, b), c, 0, 0, 0);
}

__device__ __forceinline__ float exp2fast(float x) {
#if __has_builtin(__builtin_amdgcn_exp2f)
  return __builtin_amdgcn_exp2f(x);
#else
  return exp2f(x);
#endif
}

__device__ __forceinline__ void gload_lds16(const void* g, void* l) {
  __builtin_amdgcn_global_load_lds(
      (const __attribute__((address_space(1))) unsigned int*)g,
      (__attribute__((address_space(3))) unsigned int*)l, 16, 0, 0);
}

// ---------- pre-pass: x fp32 -> bf16 ----------
__global__ __launch_bounds__(256) void convx_kernel(const float* __restrict__ x,
                                                    short* __restrict__ xb) {
  int gid = blockIdx.x * 256 + threadIdx.x;   // 524288 threads, 8 elems each
  const float4* x4 = (const float4*)x;
  float4 v0 = x4[2 * gid], v1 = x4[2 * gid + 1];
  short8 o;
  o[0] = f2bf(v0.x); o[1] = f2bf(v0.y); o[2] = f2bf(v0.z); o[3] = f2bf(v0.w);
  o[4] = f2bf(v1.x); o[5] = f2bf(v1.y); o[6] = f2bf(v1.z); o[7] = f2bf(v1.w);
  *(short8*)&xb[(size_t)gid * 8] = o;
}

// ---------- pre-pass: W [K][N] fp32 -> Wt [N][K] bf16 ----------
__global__ __launch_bounds__(256) void transw_kernel(
    const float* __restrict__ Wq, const float* __restrict__ Wk,
    const float* __restrict__ Wv, const float* __restrict__ Wmix,
    short* __restrict__ Wt, short* __restrict__ Wmixt)
{
  __shared__ float Ws[64][65];
  const float* src; short* dst;
  switch (blockIdx.z) {
    case 0:  src = Wq;   dst = Wt;                 break;
    case 1:  src = Wk;   dst = Wt + (1u << 20);    break;
    case 2:  src = Wv;   dst = Wt + (2u << 20);    break;
    default: src = Wmix; dst = Wmixt;              break;
  }
  const int n0 = blockIdx.x * 64, k0 = blockIdx.y * 64;
  const int c = threadIdx.x & 63, r0 = threadIdx.x >> 6;
  #pragma unroll
  for (int i = 0; i < 16; ++i) {
    int rr = r0 + 4 * i;
    Ws[rr][c] = src[(size_t)(k0 + rr) * DIN + n0 + c];
  }
  __syncthreads();
  #pragma unroll
  for (int i = 0; i < 16; ++i) {
    int cc = r0 + 4 * i;
    dst[(size_t)(n0 + cc) * DIN + k0 + c] = f2bf(Ws[c][cc]);
  }
}

// ---------- GEMM: C[M][N] = A[M][K]bf16 @ Bt[N][K]bf16^T + bias ----------
// QKV mode: N=3072; cols [0,2048) -> qkv buffer (bf16), cols [2048,3072)
// -> vt transposed [(b*16+h)*64+d][SEQ] (bf16).
template<int BM, int BN, bool OUT_F32, bool QKV>
__global__ __launch_bounds__(256) void gemm_kernel(
    const short* __restrict__ A, const short* __restrict__ Bt,
    const float* __restrict__ bias, void* __restrict__ Cp,
    short* __restrict__ vt, int Ndim, int Kdim)
{
  constexpr int MT = BM / 32, NT = BN / 32;
  __shared__ short As[BM * 32];
  __shared__ short Bs[BN * 32];
  const int tid = threadIdx.x;
  const int wid = tid >> 6, lane = tid & 63, lg = lane >> 4, lm = lane & 15;
  const int wr = wid >> 1, wc = wid & 1;
  const int m0 = blockIdx.y * BM, n0 = blockIdx.x * BN;

  floatx4 acc[MT][NT];
  #pragma unroll
  for (int i = 0; i < MT; ++i)
    #pragma unroll
    for (int j = 0; j < NT; ++j) acc[i][j] = floatx4{0.f, 0.f, 0.f, 0.f};

  // per-thread staging coords (chunk-XOR swizzled source, linear LDS dest)
  for (int k0 = 0; k0 < Kdim; k0 += 32) {
    __syncthreads();
    #pragma unroll
    for (int j = 0; j < BM / 64; ++j) {
      int flat = tid + 256 * j;
      int row = flat >> 2, ch = (flat & 3) ^ ((row >> 1) & 3);
      gload_lds16(A + (size_t)(m0 + row) * Kdim + k0 + ch * 8,
                  (char*)As + wid * 1024 + j * 4096);
    }
    #pragma unroll
    for (int j = 0; j < BN / 64; ++j) {
      int flat = tid + 256 * j;
      int row = flat >> 2, ch = (flat & 3) ^ ((row >> 1) & 3);
      gload_lds16(Bt + (size_t)(n0 + row) * Kdim + k0 + ch * 8,
                  (char*)Bs + wid * 1024 + j * 4096);
    }
    __syncthreads();

    short8 a[MT], b[NT];
    #pragma unroll
    for (int mt = 0; mt < MT; ++mt) {
      int row = wr * (BM / 2) + mt * 16 + lm;
      a[mt] = *(const short8*)&As[row * 32 + (lg ^ ((row >> 1) & 3)) * 8];
    }
    #pragma unroll
    for (int nt = 0; nt < NT; ++nt) {
      int row = wc * (BN / 2) + nt * 16 + lm;
      b[nt] = *(const short8*)&Bs[row * 32 + (lg ^ ((row >> 1) & 3)) * 8];
    }
    #pragma unroll
    for (int mt = 0; mt < MT; ++mt)
      #pragma unroll
      for (int nt = 0; nt < NT; ++nt)
        acc[mt][nt] = mfma16(a[mt], b[nt], acc[mt][nt]);
  }

  #pragma unroll
  for (int mt = 0; mt < MT; ++mt) {
    const int row0 = m0 + wr * (BM / 2) + mt * 16 + 4 * lg;
    #pragma unroll
    for (int nt = 0; nt < NT; ++nt) {
      const int col = n0 + wc * (BN / 2) + nt * 16 + lm;
      const float bv = bias[col];
      if (QKV && n0 >= 2048) {
        // V range: write transposed to vt
        int hd = col - 2048;
        int bb = row0 >> 11, s = row0 & 2047;
        short4v pv;
        #pragma unroll
        for (int r = 0; r < 4; ++r) pv[r] = f2bf(acc[mt][nt][r] + bv);
        *(short4v*)&vt[((size_t)(bb * (NH * HD) + hd)) * SEQ + s] = pv;
      } else {
        #pragma unroll
        for (int r = 0; r < 4; ++r) {
          float v = acc[mt][nt][r] + bv;
          if (OUT_F32) ((float*)Cp)[(size_t)(row0 + r) * Ndim + col] = v;
          else         ((short*)Cp)[(size_t)(row0 + r) * Ndim + col] = f2bf(v);
        }
      }
    }
  }
}

// ---------- flash attention ----------
// qkv: [M_ROWS][3072] bf16 (q | k | unused-v), vt: [(b*16+h)*64+d][SEQ] bf16
__global__ __launch_bounds__(256) void attn_kernel(
    const short* __restrict__ qkv, const short* __restrict__ vt,
    short* __restrict__ att)
{
  __shared__ short Ks[64][72];     // [kv][d]
  __shared__ short Vs[64][72];     // [d][kv]  (from vt, no transpose needed)
  __shared__ short Ps[4][16][72];  // per-wave P strip
  const int tid = threadIdx.x;
  const int wid = tid >> 6, lane = tid & 63, lg = lane >> 4, lm = lane & 15;
  const int q0 = blockIdx.x * 64, bh = blockIdx.y, b = bh >> 4, h = bh & 15;
  const short* qp = qkv + (size_t)(b * SEQ) * NQKV + h * HD;
  const short* kp = qp + HID;
  const short* vp = vt + (size_t)bh * HD * SEQ;

  short8 qf[2];
  {
    const short* qrow = qp + (size_t)(q0 + wid * 16 + lm) * NQKV;
    qf[0] = *(const short8*)(qrow + lg * 8);
    qf[1] = *(const short8*)(qrow + 32 + lg * 8);
  }

  const int rstage = tid >> 3, c8 = (tid & 7) * 8;
  short8 kreg[2], vreg[2];
  #pragma unroll
  for (int i = 0; i < 2; ++i) {
    kreg[i] = *(const short8*)(kp + (size_t)(rstage + 32 * i) * NQKV + c8);
    vreg[i] = *(const short8*)(vp + (size_t)(rstage + 32 * i) * SEQ + c8);
  }

  float mrow[4], lrow[4];
  floatx4 o[4];
  #pragma unroll
  for (int r = 0; r < 4; ++r) { mrow[r] = -3e38f; lrow[r] = 0.f; }
  #pragma unroll
  for (int nt = 0; nt < 4; ++nt) o[nt] = floatx4{0.f, 0.f, 0.f, 0.f};

  const int ntile = blockIdx.x + 1;
  const float cl2 = 0.18033688011112042f;   // log2(e)/8  (scale 1/sqrt(64))

  for (int t = 0; t < ntile; ++t) {
    __syncthreads();                 // prev tile LDS reads done
    #pragma unroll
    for (int i = 0; i < 2; ++i) {
      *(short8*)&Ks[rstage + 32 * i][c8] = kreg[i];
      *(short8*)&Vs[rstage + 32 * i][c8] = vreg[i];
    }
    __syncthreads();
    if (t + 1 < ntile) {             // prefetch next tile into regs (T14)
      const int kv1 = (t + 1) * 64;
      #pragma unroll
      for (int i = 0; i < 2; ++i) {
        kreg[i] = *(const short8*)(kp + (size_t)(kv1 + rstage + 32 * i) * NQKV + c8);
        vreg[i] = *(const short8*)(vp + (size_t)(rstage + 32 * i) * SEQ + kv1 + c8);
      }
    }

    // S = Q K^T
    floatx4 s[4];
    #pragma unroll
    for (int nt = 0; nt < 4; ++nt) s[nt] = floatx4{0.f, 0.f, 0.f, 0.f};
    #pragma unroll
    for (int kk = 0; kk < 2; ++kk)
      #pragma unroll
      for (int nt = 0; nt < 4; ++nt)
        s[nt] = mfma16(qf[kk], *(const short8*)&Ks[nt * 16 + lm][kk * 32 + lg * 8], s[nt]);

    // softmax (log2 domain)
    float p[4][4], pm[4];
    #pragma unroll
    for (int r = 0; r < 4; ++r) pm[r] = -3e38f;
    if (t == blockIdx.x) {           // diagonal tile: causal mask
      #pragma unroll
      for (int nt = 0; nt < 4; ++nt)
        #pragma unroll
        for (int r = 0; r < 4; ++r) {
          int qrow = q0 + wid * 16 + 4 * lg + r;
          int kcol = t * 64 + nt * 16 + lm;
          float val = s[nt][r] * cl2;
          if (kcol > qrow) val = -3e38f;
          p[nt][r] = val; pm[r] = fmaxf(pm[r], val);
        }
    } else {
      #pragma unroll
      for (int nt = 0; nt < 4; ++nt)
        #pragma unroll
        for (int r = 0; r < 4; ++r) {
          float val = s[nt][r] * cl2;
          p[nt][r] = val; pm[r] = fmaxf(pm[r], val);
        }
    }
    #pragma unroll
    for (int r = 0; r < 4; ++r)
      #pragma unroll
      for (int off = 1; off < 16; off <<= 1)
        pm[r] = fmaxf(pm[r], __shfl_xor(pm[r], off));

    float corr[4], psum[4];
    #pragma unroll
    for (int r = 0; r < 4; ++r) {
      float mnew = fmaxf(mrow[r], pm[r]);
      corr[r] = exp2fast(mrow[r] - mnew);
      mrow[r] = mnew; psum[r] = 0.f;
    }
    #pragma unroll
    for (int nt = 0; nt < 4; ++nt)
      #pragma unroll
      for (int r = 0; r < 4; ++r) {
        float e = exp2fast(p[nt][r] - mrow[r]);
        p[nt][r] = e; psum[r] += e;
      }
    #pragma unroll
    for (int r = 0; r < 4; ++r) {
      #pragma unroll
      for (int off = 1; off < 16; off <<= 1)
        psum[r] += __shfl_xor(psum[r], off);
      lrow[r] = lrow[r] * corr[r] + psum[r];
    }
    #pragma unroll
    for (int nt = 0; nt < 4; ++nt)
      #pragma unroll
      for (int r = 0; r < 4; ++r) o[nt][r] *= corr[r];

    // P -> LDS (per-wave strip; no barrier needed) -> A-frag
    #pragma unroll
    for (int nt = 0; nt < 4; ++nt)
      #pragma unroll
      for (int r = 0; r < 4; ++r)
        Ps[wid][4 * lg + r][nt * 16 + lm] = f2bf(p[nt][r]);

    #pragma unroll
    for (int kk = 0; kk < 2; ++kk) {
      short8 pf = *(const short8*)&Ps[wid][lm][kk * 32 + lg * 8];
      #pragma unroll
      for (int nt = 0; nt < 4; ++nt)
        o[nt] = mfma16(pf, *(const short8*)&Vs[nt * 16 + lm][kk * 32 + lg * 8], o[nt]);
    }
  }

  float linv[4];
  #pragma unroll
  for (int r = 0; r < 4; ++r) linv[r] = 1.0f / lrow[r];
  #pragma unroll
  for (int nt = 0; nt < 4; ++nt)
    #pragma unroll
    for (int r = 0; r < 4; ++r) {
      int row = q0 + wid * 16 + 4 * lg + r;
      int col = h * HD + nt * 16 + lm;
      att[((size_t)(b * SEQ + row)) * HID + col] = f2bf(o[nt][r] * linv[r]);
    }
}

extern "C" void kernel_launch(void* const* d_in, const int* in_sizes, int n_in,
                              void* d_out, int out_size, void* d_ws, size_t ws_size,
                              hipStream_t stream) {
  (void)in_sizes; (void)n_in; (void)out_size; (void)ws_size;
  const float* x    = (const float*)d_in[0];
  const float* Wq   = (const float*)d_in[1];
  const float* bq   = (const float*)d_in[2];
  const float* Wk   = (const float*)d_in[3];
  const float* bk   = (const float*)d_in[4];
  const float* Wv   = (const float*)d_in[5];
  const float* bv   = (const float*)d_in[6];
  const float* Wmix = (const float*)d_in[7];
  const float* bmix = (const float*)d_in[8];
  float* out = (float*)d_out;

  char* w = (char*)d_ws;
  short* xb      = (short*)w; w += (size_t)8 << 20;   // [4096][1024] bf16
  short* Wt      = (short*)w; w += (size_t)6 << 20;   // [3072][1024] bf16 (q|k|v rows)
  short* Wmixt   = (short*)w; w += (size_t)2 << 20;   // [1024][1024] bf16
  float* biascat = (float*)w; w += (size_t)16 << 10;  // [3072]
  short* qkvb    = (short*)w; w += (size_t)24 << 20;  // [4096][3072] bf16
  short* vtb     = (short*)w; w += (size_t)8 << 20;   // [2048][2048] bf16
  short* ab      = (short*)w;                          // [4096][1024] bf16

  hipLaunchKernelGGL(convx_kernel, dim3(2048), dim3(256), 0, stream, x, xb);
  hipLaunchKernelGGL(transw_kernel, dim3(16, 16, 4), dim3(256), 0, stream,
                     Wq, Wk, Wv, Wmix, Wt, Wmixt);
  hipMemcpyAsync(biascat,        bq, 1024 * sizeof(float), hipMemcpyDeviceToDevice, stream);
  hipMemcpyAsync(biascat + 1024, bk, 1024 * sizeof(float), hipMemcpyDeviceToDevice, stream);
  hipMemcpyAsync(biascat + 2048, bv, 1024 * sizeof(float), hipMemcpyDeviceToDevice, stream);

  hipLaunchKernelGGL((gemm_kernel<128, 128, false, true>), dim3(NQKV / 128, M_ROWS / 128),
                     dim3(256), 0, stream, xb, Wt, biascat, (void*)qkvb, vtb, NQKV, DIN);

  hipLaunchKernelGGL(attn_kernel, dim3(SEQ / 64, BS * NH), dim3(256), 0, stream,
                     qkvb, vtb, ab);

  hipLaunchKernelGGL((gemm_kernel<64, 128, true, false>), dim3(HID / 128, M_ROWS / 64),
                     dim3(256), 0, stream, ab, Wmixt, bmix, (void*)out, (short*)nullptr,
                     HID, DIN);
}

// Round 3
// 152.633 us; speedup vs baseline: 2.1152x; 1.2757x over previous
//
#include <hip/hip_runtime.h>
#include <hip/hip_bf16.h>

#define BS 2
#define SEQ 2048
#define DIN 1024
#define HID 1024
#define NH 16
#define HD 64
#define M_ROWS (BS*SEQ)
#define NQKV 3072

typedef __attribute__((ext_vector_type(8))) short short8;
typedef __attribute__((ext_vector_type(4))) short short4v;
typedef __attribute__((ext_vector_type(8))) __bf16 bf16x8;
typedef __attribute__((ext_vector_type(4))) float floatx4;

__device__ __forceinline__ short f2bf(float f) {
  unsigned u = __float_as_uint(f);
  u += 0x7fffu + ((u >> 16) & 1u);
  return (short)(u >> 16);
}
__device__ __forceinline__ float bf2f(short s) {
  return __uint_as_float(((unsigned)(unsigned short)s) << 16);
}

__device__ __forceinline__ floatx4 mfma16(short8 a, short8 b, floatx4 c) {
  return __builtin_amdgcn_mfma_f32_16x16x32_bf16(
      __builtin_bit_cast(bf16x8, a), __builtin_bit_cast(bf16x8, b), c, 0, 0, 0);
}

__device__ __forceinline__ float exp2fast(float x) {
#if __has_builtin(__builtin_amdgcn_exp2f)
  return __builtin_amdgcn_exp2f(x);
#else
  return exp2f(x);
#endif
}

__device__ __forceinline__ void gload_lds16(const void* g, void* l) {
  __builtin_amdgcn_global_load_lds(
      (const __attribute__((address_space(1))) unsigned int*)g,
      (__attribute__((address_space(3))) unsigned int*)l, 16, 0, 0);
}

// ---------- pre-pass: x fp32 -> bf16 ----------
__global__ __launch_bounds__(256) void convx_kernel(const float* __restrict__ x,
                                                    short* __restrict__ xb) {
  int gid = blockIdx.x * 256 + threadIdx.x;
  const float4* x4 = (const float4*)x;
  float4 v0 = x4[2 * gid], v1 = x4[2 * gid + 1];
  short8 o;
  o[0] = f2bf(v0.x); o[1] = f2bf(v0.y); o[2] = f2bf(v0.z); o[3] = f2bf(v0.w);
  o[4] = f2bf(v1.x); o[5] = f2bf(v1.y); o[6] = f2bf(v1.z); o[7] = f2bf(v1.w);
  *(short8*)&xb[(size_t)gid * 8] = o;
}

// ---------- pre-pass: W [K][N] fp32 -> Wt [N][K] bf16 ----------
__global__ __launch_bounds__(256) void transw_kernel(
    const float* __restrict__ Wq, const float* __restrict__ Wk,
    const float* __restrict__ Wv, const float* __restrict__ Wmix,
    short* __restrict__ Wt, short* __restrict__ Wmixt)
{
  __shared__ float Ws[64][65];
  const float* src; short* dst;
  switch (blockIdx.z) {
    case 0:  src = Wq;   dst = Wt;                 break;
    case 1:  src = Wk;   dst = Wt + (1u << 20);    break;
    case 2:  src = Wv;   dst = Wt + (2u << 20);    break;
    default: src = Wmix; dst = Wmixt;              break;
  }
  const int n0 = blockIdx.x * 64, k0 = blockIdx.y * 64;
  const int c = threadIdx.x & 63, r0 = threadIdx.x >> 6;
  #pragma unroll
  for (int i = 0; i < 16; ++i) {
    int rr = r0 + 4 * i;
    Ws[rr][c] = src[(size_t)(k0 + rr) * DIN + n0 + c];
  }
  __syncthreads();
  #pragma unroll
  for (int i = 0; i < 16; ++i) {
    int cc = r0 + 4 * i;
    dst[(size_t)(n0 + cc) * DIN + k0 + c] = f2bf(Ws[c][cc]);
  }
}

// ---------- GEMM: C[M][N] = A[M][K]bf16 @ Bt[N][K]bf16^T + bias ----------
template<int BM, int BN, bool OUT_F32, bool QKV>
__global__ __launch_bounds__(256) void gemm_kernel(
    const short* __restrict__ A, const short* __restrict__ Bt,
    const float* __restrict__ bias, void* __restrict__ Cp,
    short* __restrict__ vt, int Ndim, int Kdim)
{
  constexpr int MT = BM / 32, NT = BN / 32;
  __shared__ short As[BM * 32];
  __shared__ short Bs[BN * 32];
  const int tid = threadIdx.x;
  const int wid = tid >> 6, lane = tid & 63, lg = lane >> 4, lm = lane & 15;
  const int wr = wid >> 1, wc = wid & 1;
  const int m0 = blockIdx.y * BM, n0 = blockIdx.x * BN;

  floatx4 acc[MT][NT];
  #pragma unroll
  for (int i = 0; i < MT; ++i)
    #pragma unroll
    for (int j = 0; j < NT; ++j) acc[i][j] = floatx4{0.f, 0.f, 0.f, 0.f};

  for (int k0 = 0; k0 < Kdim; k0 += 32) {
    __syncthreads();
    #pragma unroll
    for (int j = 0; j < BM / 64; ++j) {
      int flat = tid + 256 * j;
      int row = flat >> 2, ch = (flat & 3) ^ ((row >> 1) & 3);
      gload_lds16(A + (size_t)(m0 + row) * Kdim + k0 + ch * 8,
                  (char*)As + wid * 1024 + j * 4096);
    }
    #pragma unroll
    for (int j = 0; j < BN / 64; ++j) {
      int flat = tid + 256 * j;
      int row = flat >> 2, ch = (flat & 3) ^ ((row >> 1) & 3);
      gload_lds16(Bt + (size_t)(n0 + row) * Kdim + k0 + ch * 8,
                  (char*)Bs + wid * 1024 + j * 4096);
    }
    __syncthreads();

    short8 a[MT], b[NT];
    #pragma unroll
    for (int mt = 0; mt < MT; ++mt) {
      int row = wr * (BM / 2) + mt * 16 + lm;
      a[mt] = *(const short8*)&As[row * 32 + (lg ^ ((row >> 1) & 3)) * 8];
    }
    #pragma unroll
    for (int nt = 0; nt < NT; ++nt) {
      int row = wc * (BN / 2) + nt * 16 + lm;
      b[nt] = *(const short8*)&Bs[row * 32 + (lg ^ ((row >> 1) & 3)) * 8];
    }
    #pragma unroll
    for (int mt = 0; mt < MT; ++mt)
      #pragma unroll
      for (int nt = 0; nt < NT; ++nt)
        acc[mt][nt] = mfma16(a[mt], b[nt], acc[mt][nt]);
  }

  #pragma unroll
  for (int mt = 0; mt < MT; ++mt) {
    const int row0 = m0 + wr * (BM / 2) + mt * 16 + 4 * lg;
    #pragma unroll
    for (int nt = 0; nt < NT; ++nt) {
      const int col = n0 + wc * (BN / 2) + nt * 16 + lm;
      const float bv = bias[col];
      if (QKV && n0 >= 2048) {
        int hd = col - 2048;
        int bb = row0 >> 11, s = row0 & 2047;
        short4v pv;
        #pragma unroll
        for (int r = 0; r < 4; ++r) pv[r] = f2bf(acc[mt][nt][r] + bv);
        *(short4v*)&vt[((size_t)(bb * (NH * HD) + hd)) * SEQ + s] = pv;
      } else {
        #pragma unroll
        for (int r = 0; r < 4; ++r) {
          float v = acc[mt][nt][r] + bv;
          if (OUT_F32) ((float*)Cp)[(size_t)(row0 + r) * Ndim + col] = v;
          else         ((short*)Cp)[(size_t)(row0 + r) * Ndim + col] = f2bf(v);
        }
      }
    }
  }
}

// ---------- split-KV flash attention ----------
// Block = (id, bh). id in [0,80) maps to (q-tile x, chunk c of 8 kv-tiles).
// nch==1 -> write final att; else write partial O (bf16) + m,l (fp32, log2).
__global__ __launch_bounds__(256) void attn_kernel(
    const short* __restrict__ qkv, const short* __restrict__ vt,
    short* __restrict__ att, short* __restrict__ pO, float* __restrict__ pml)
{
  __shared__ short Ks[64][72];
  __shared__ short Vs[64][72];
  __shared__ short Ps[4][16][72];
  const int tid = threadIdx.x;
  const int wid = tid >> 6, lane = tid & 63, lg = lane >> 4, lm = lane & 15;

  int id = blockIdx.x, x, c, nch;
  if (id < 8)       { x = id;                      c = 0;                nch = 1; }
  else if (id < 24) { int t2 = id - 8;  x = 8  + (t2 >> 1); c = t2 & 1;  nch = 2; }
  else if (id < 48) { int t2 = id - 24; x = 16 + t2 / 3;    c = t2 % 3;  nch = 3; }
  else              { int t2 = id - 48; x = 24 + (t2 >> 2); c = t2 & 3;  nch = 4; }
  const int tb = c * 8;
  const int te = min(tb + 8, x + 1);
  const int q0 = x * 64;
  const int bh = blockIdx.y, b = bh >> 4, h = bh & 15;
  const short* qp = qkv + (size_t)(b * SEQ) * NQKV + h * HD;
  const short* kp = qp + HID;
  const short* vp = vt + (size_t)bh * HD * SEQ;

  // Q fragments, pre-scaled by log2(e)/sqrt(D)
  const float cl2 = 0.18033688011112042f;
  short8 qf[2];
  {
    const short* qrow = qp + (size_t)(q0 + wid * 16 + lm) * NQKV;
    #pragma unroll
    for (int kk = 0; kk < 2; ++kk) {
      short8 raw = *(const short8*)(qrow + kk * 32 + lg * 8);
      #pragma unroll
      for (int j = 0; j < 8; ++j) qf[kk][j] = f2bf(bf2f(raw[j]) * cl2);
    }
  }

  const int rstage = tid >> 3, c8 = (tid & 7) * 8;
  short8 kreg[2], vreg[2];
  #pragma unroll
  for (int i = 0; i < 2; ++i) {
    kreg[i] = *(const short8*)(kp + (size_t)(tb * 64 + rstage + 32 * i) * NQKV + c8);
    vreg[i] = *(const short8*)(vp + (size_t)(rstage + 32 * i) * SEQ + tb * 64 + c8);
  }

  float mrow[4], lrow[4];
  floatx4 o[4];
  #pragma unroll
  for (int r = 0; r < 4; ++r) { mrow[r] = -3e38f; lrow[r] = 0.f; }
  #pragma unroll
  for (int nt = 0; nt < 4; ++nt) o[nt] = floatx4{0.f, 0.f, 0.f, 0.f};

  for (int t = tb; t < te; ++t) {
    __syncthreads();
    #pragma unroll
    for (int i = 0; i < 2; ++i) {
      *(short8*)&Ks[rstage + 32 * i][c8] = kreg[i];
      *(short8*)&Vs[rstage + 32 * i][c8] = vreg[i];
    }
    __syncthreads();
    if (t + 1 < te) {
      const int kv1 = (t + 1) * 64;
      #pragma unroll
      for (int i = 0; i < 2; ++i) {
        kreg[i] = *(const short8*)(kp + (size_t)(kv1 + rstage + 32 * i) * NQKV + c8);
        vreg[i] = *(const short8*)(vp + (size_t)(rstage + 32 * i) * SEQ + kv1 + c8);
      }
    }

    floatx4 s[4];
    #pragma unroll
    for (int nt = 0; nt < 4; ++nt) s[nt] = floatx4{0.f, 0.f, 0.f, 0.f};
    #pragma unroll
    for (int kk = 0; kk < 2; ++kk)
      #pragma unroll
      for (int nt = 0; nt < 4; ++nt)
        s[nt] = mfma16(qf[kk], *(const short8*)&Ks[nt * 16 + lm][kk * 32 + lg * 8], s[nt]);

    float p[4][4], pm[4];
    #pragma unroll
    for (int r = 0; r < 4; ++r) pm[r] = -3e38f;
    if (t == x) {
      #pragma unroll
      for (int nt = 0; nt < 4; ++nt)
        #pragma unroll
        for (int r = 0; r < 4; ++r) {
          int qrow = q0 + wid * 16 + 4 * lg + r;
          int kcol = t * 64 + nt * 16 + lm;
          float val = s[nt][r];
          if (kcol > qrow) val = -3e38f;
          p[nt][r] = val; pm[r] = fmaxf(pm[r], val);
        }
    } else {
      #pragma unroll
      for (int nt = 0; nt < 4; ++nt)
        #pragma unroll
        for (int r = 0; r < 4; ++r) {
          float val = s[nt][r];
          p[nt][r] = val; pm[r] = fmaxf(pm[r], val);
        }
    }
    #pragma unroll
    for (int r = 0; r < 4; ++r)
      #pragma unroll
      for (int off = 1; off < 16; off <<= 1)
        pm[r] = fmaxf(pm[r], __shfl_xor(pm[r], off));

    float corr[4], psum[4];
    #pragma unroll
    for (int r = 0; r < 4; ++r) {
      float mnew = fmaxf(mrow[r], pm[r]);
      corr[r] = exp2fast(mrow[r] - mnew);
      mrow[r] = mnew; psum[r] = 0.f;
    }
    #pragma unroll
    for (int nt = 0; nt < 4; ++nt)
      #pragma unroll
      for (int r = 0; r < 4; ++r) {
        float e = exp2fast(p[nt][r] - mrow[r]);
        p[nt][r] = e; psum[r] += e;
      }
    #pragma unroll
    for (int r = 0; r < 4; ++r) {
      #pragma unroll
      for (int off = 1; off < 16; off <<= 1)
        psum[r] += __shfl_xor(psum[r], off);
      lrow[r] = lrow[r] * corr[r] + psum[r];
    }
    #pragma unroll
    for (int nt = 0; nt < 4; ++nt)
      #pragma unroll
      for (int r = 0; r < 4; ++r) o[nt][r] *= corr[r];

    #pragma unroll
    for (int nt = 0; nt < 4; ++nt)
      #pragma unroll
      for (int r = 0; r < 4; ++r)
        Ps[wid][4 * lg + r][nt * 16 + lm] = f2bf(p[nt][r]);

    #pragma unroll
    for (int kk = 0; kk < 2; ++kk) {
      short8 pf = *(const short8*)&Ps[wid][lm][kk * 32 + lg * 8];
      #pragma unroll
      for (int nt = 0; nt < 4; ++nt)
        o[nt] = mfma16(pf, *(const short8*)&Vs[nt * 16 + lm][kk * 32 + lg * 8], o[nt]);
    }
  }

  if (nch == 1) {
    float linv[4];
    #pragma unroll
    for (int r = 0; r < 4; ++r) linv[r] = 1.0f / lrow[r];
    #pragma unroll
    for (int nt = 0; nt < 4; ++nt)
      #pragma unroll
      for (int r = 0; r < 4; ++r) {
        int row = q0 + wid * 16 + 4 * lg + r;
        int col = h * HD + nt * 16 + lm;
        att[((size_t)(b * SEQ + row)) * HID + col] = f2bf(o[nt][r] * linv[r]);
      }
  } else {
    const int slot = (bh * 24 + (x - 8)) * 4 + c;
    short* po = pO + (size_t)slot * 4096;
    #pragma unroll
    for (int nt = 0; nt < 4; ++nt)
      #pragma unroll
      for (int r = 0; r < 4; ++r) {
        int row = wid * 16 + 4 * lg + r;
        po[row * 64 + nt * 16 + lm] = f2bf(o[nt][r]);
      }
    if (lm == 0) {
      #pragma unroll
      for (int r = 0; r < 4; ++r) {
        int row = wid * 16 + 4 * lg + r;
        pml[slot * 128 + row] = mrow[r];
        pml[slot * 128 + 64 + row] = lrow[r];
      }
    }
  }
}

// ---------- combine partials: grid (24, 32) ----------
__global__ __launch_bounds__(256) void combine_kernel(
    const short* __restrict__ pO, const float* __restrict__ pml,
    short* __restrict__ att)
{
  const int x = 8 + blockIdx.x;
  const int bh = blockIdx.y, b = bh >> 4, h = bh & 15;
  const int nch = (x >> 3) + 1;          // 2, 3, or 4
  const int tid = threadIdx.x;
  const int row = tid >> 2, d0 = (tid & 3) * 16;
  const int base_slot = (bh * 24 + (x - 8)) * 4;

  float mv[4], lv[4], M = -3e38f;
  for (int cc = 0; cc < nch; ++cc) {
    mv[cc] = pml[(base_slot + cc) * 128 + row];
    lv[cc] = pml[(base_slot + cc) * 128 + 64 + row];
    M = fmaxf(M, mv[cc]);
  }
  float L = 0.f, w[4];
  for (int cc = 0; cc < nch; ++cc) {
    w[cc] = exp2fast(mv[cc] - M);
    L += lv[cc] * w[cc];
  }
  const float inv = 1.0f / L;

  float acc[16];
  #pragma unroll
  for (int j = 0; j < 16; ++j) acc[j] = 0.f;
  for (int cc = 0; cc < nch; ++cc) {
    const short* po = pO + (size_t)(base_slot + cc) * 4096 + row * 64 + d0;
    short8 v0 = *(const short8*)po, v1 = *(const short8*)(po + 8);
    #pragma unroll
    for (int j = 0; j < 8; ++j) {
      acc[j]     += bf2f(v0[j]) * w[cc];
      acc[j + 8] += bf2f(v1[j]) * w[cc];
    }
  }
  short8 o0, o1;
  #pragma unroll
  for (int j = 0; j < 8; ++j) {
    o0[j] = f2bf(acc[j] * inv);
    o1[j] = f2bf(acc[j + 8] * inv);
  }
  short* dst = att + ((size_t)(b * SEQ + x * 64 + row)) * HID + h * HD + d0;
  *(short8*)dst = o0;
  *(short8*)(dst + 8) = o1;
}

extern "C" void kernel_launch(void* const* d_in, const int* in_sizes, int n_in,
                              void* d_out, int out_size, void* d_ws, size_t ws_size,
                              hipStream_t stream) {
  (void)in_sizes; (void)n_in; (void)out_size; (void)ws_size;
  const float* x    = (const float*)d_in[0];
  const float* Wq   = (const float*)d_in[1];
  const float* bq   = (const float*)d_in[2];
  const float* Wk   = (const float*)d_in[3];
  const float* bk   = (const float*)d_in[4];
  const float* Wv   = (const float*)d_in[5];
  const float* bv   = (const float*)d_in[6];
  const float* Wmix = (const float*)d_in[7];
  const float* bmix = (const float*)d_in[8];
  float* out = (float*)d_out;

  char* w = (char*)d_ws;
  short* xb      = (short*)w; w += (size_t)8 << 20;
  short* Wt      = (short*)w; w += (size_t)6 << 20;
  short* Wmixt   = (short*)w; w += (size_t)2 << 20;
  float* biascat = (float*)w; w += (size_t)64 << 10;
  short* qkvb    = (short*)w; w += (size_t)24 << 20;
  short* vtb     = (short*)w; w += (size_t)8 << 20;
  short* ab      = (short*)w; w += (size_t)8 << 20;
  short* pO      = (short*)w; w += (size_t)3072 * 4096 * 2;
  float* pml     = (float*)w;

  hipLaunchKernelGGL(convx_kernel, dim3(2048), dim3(256), 0, stream, x, xb);
  hipLaunchKernelGGL(transw_kernel, dim3(16, 16, 4), dim3(256), 0, stream,
                     Wq, Wk, Wv, Wmix, Wt, Wmixt);
  hipMemcpyAsync(biascat,        bq, 1024 * sizeof(float), hipMemcpyDeviceToDevice, stream);
  hipMemcpyAsync(biascat + 1024, bk, 1024 * sizeof(float), hipMemcpyDeviceToDevice, stream);
  hipMemcpyAsync(biascat + 2048, bv, 1024 * sizeof(float), hipMemcpyDeviceToDevice, stream);

  hipLaunchKernelGGL((gemm_kernel<128, 128, false, true>), dim3(NQKV / 128, M_ROWS / 128),
                     dim3(256), 0, stream, xb, Wt, biascat, (void*)qkvb, vtb, NQKV, DIN);

  hipLaunchKernelGGL(attn_kernel, dim3(80, BS * NH), dim3(256), 0, stream,
                     qkvb, vtb, ab, pO, pml);
  hipLaunchKernelGGL(combine_kernel, dim3(24, BS * NH), dim3(256), 0, stream,
                     pO, pml, ab);

  hipLaunchKernelGGL((gemm_kernel<64, 128, true, false>), dim3(HID / 128, M_ROWS / 64),
                     dim3(256), 0, stream, ab, Wmixt, bmix, (void*)out, (short*)nullptr,
                     HID, DIN);
}

// Round 4
// 150.816 us; speedup vs baseline: 2.1407x; 1.0120x over previous
//
#include <hip/hip_runtime.h>
#include <hip/hip_bf16.h>

#define BS 2
#define SEQ 2048
#define DIN 1024
#define HID 1024
#define NH 16
#define HD 64
#define M_ROWS (BS*SEQ)
#define NQKV 3072

typedef __attribute__((ext_vector_type(8))) short short8;
typedef __attribute__((ext_vector_type(4))) short short4v;
typedef __attribute__((ext_vector_type(8))) __bf16 bf16x8;
typedef __attribute__((ext_vector_type(4))) float floatx4;

__device__ __forceinline__ short f2bf(float f) {
  unsigned u = __float_as_uint(f);
  u += 0x7fffu + ((u >> 16) & 1u);
  return (short)(u >> 16);
}
__device__ __forceinline__ float bf2f(short s) {
  return __uint_as_float(((unsigned)(unsigned short)s) << 16);
}

__device__ __forceinline__ floatx4 mfma16(short8 a, short8 b, floatx4 c) {
  return __builtin_amdgcn_mfma_f32_16x16x32_bf16(
      __builtin_bit_cast(bf16x8, a), __builtin_bit_cast(bf16x8, b), c, 0, 0, 0);
}

__device__ __forceinline__ float exp2fast(float x) {
#if __has_builtin(__builtin_amdgcn_exp2f)
  return __builtin_amdgcn_exp2f(x);
#else
  return exp2f(x);
#endif
}

__device__ __forceinline__ void gload_lds16(const void* g, void* l) {
  __builtin_amdgcn_global_load_lds(
      (const __attribute__((address_space(1))) unsigned int*)g,
      (__attribute__((address_space(3))) unsigned int*)l, 16, 0, 0);
}

// XOR-swizzled LDS helpers (row stride 72 shorts = 144B; key = (row&7)<<4)
__device__ __forceinline__ void lds_w8(short* base, int row, int colsh, short8 v) {
  char* p = (char*)base + row * 144 + ((colsh * 2) ^ ((row & 7) << 4));
  *(short8*)p = v;
}
__device__ __forceinline__ void lds_w4(short* base, int row, int colsh, short4v v) {
  char* p = (char*)base + row * 144 + ((colsh * 2) ^ ((row & 7) << 4));
  *(short4v*)p = v;
}
__device__ __forceinline__ short8 lds_r8(const short* base, int row, int colsh) {
  const char* p = (const char*)base + row * 144 + ((colsh * 2) ^ ((row & 7) << 4));
  return *(const short8*)p;
}

// ---------- pre-pass: x fp32 -> bf16 ----------
__global__ __launch_bounds__(256) void convx_kernel(const float* __restrict__ x,
                                                    short* __restrict__ xb) {
  int gid = blockIdx.x * 256 + threadIdx.x;
  const float4* x4 = (const float4*)x;
  float4 v0 = x4[2 * gid], v1 = x4[2 * gid + 1];
  short8 o;
  o[0] = f2bf(v0.x); o[1] = f2bf(v0.y); o[2] = f2bf(v0.z); o[3] = f2bf(v0.w);
  o[4] = f2bf(v1.x); o[5] = f2bf(v1.y); o[6] = f2bf(v1.z); o[7] = f2bf(v1.w);
  *(short8*)&xb[(size_t)gid * 8] = o;
}

// ---------- pre-pass: W [K][N] fp32 -> Wt [N][K] bf16 ----------
__global__ __launch_bounds__(256) void transw_kernel(
    const float* __restrict__ Wq, const float* __restrict__ Wk,
    const float* __restrict__ Wv, const float* __restrict__ Wmix,
    short* __restrict__ Wt, short* __restrict__ Wmixt)
{
  __shared__ float Ws[64][65];
  const float* src; short* dst;
  switch (blockIdx.z) {
    case 0:  src = Wq;   dst = Wt;                 break;
    case 1:  src = Wk;   dst = Wt + (1u << 20);    break;
    case 2:  src = Wv;   dst = Wt + (2u << 20);    break;
    default: src = Wmix; dst = Wmixt;              break;
  }
  const int n0 = blockIdx.x * 64, k0 = blockIdx.y * 64;
  const int c = threadIdx.x & 63, r0 = threadIdx.x >> 6;
  #pragma unroll
  for (int i = 0; i < 16; ++i) {
    int rr = r0 + 4 * i;
    Ws[rr][c] = src[(size_t)(k0 + rr) * DIN + n0 + c];
  }
  __syncthreads();
  #pragma unroll
  for (int i = 0; i < 16; ++i) {
    int cc = r0 + 4 * i;
    dst[(size_t)(n0 + cc) * DIN + k0 + c] = f2bf(Ws[c][cc]);
  }
}

// ---------- GEMM: C[M][N] = A[M][K]bf16 @ Bt[N][K]bf16^T + bias ----------
template<int BM, int BN, bool OUT_F32, bool QKV>
__global__ __launch_bounds__(256) void gemm_kernel(
    const short* __restrict__ A, const short* __restrict__ Bt,
    const float* __restrict__ bias, void* __restrict__ Cp,
    short* __restrict__ vt, int Ndim, int Kdim)
{
  constexpr int MT = BM / 32, NT = BN / 32;
  __shared__ short As[BM * 32];
  __shared__ short Bs[BN * 32];
  const int tid = threadIdx.x;
  const int wid = tid >> 6, lane = tid & 63, lg = lane >> 4, lm = lane & 15;
  const int wr = wid >> 1, wc = wid & 1;
  const int m0 = blockIdx.y * BM, n0 = blockIdx.x * BN;

  floatx4 acc[MT][NT];
  #pragma unroll
  for (int i = 0; i < MT; ++i)
    #pragma unroll
    for (int j = 0; j < NT; ++j) acc[i][j] = floatx4{0.f, 0.f, 0.f, 0.f};

  for (int k0 = 0; k0 < Kdim; k0 += 32) {
    __syncthreads();
    #pragma unroll
    for (int j = 0; j < BM / 64; ++j) {
      int flat = tid + 256 * j;
      int row = flat >> 2, ch = (flat & 3) ^ ((row >> 1) & 3);
      gload_lds16(A + (size_t)(m0 + row) * Kdim + k0 + ch * 8,
                  (char*)As + wid * 1024 + j * 4096);
    }
    #pragma unroll
    for (int j = 0; j < BN / 64; ++j) {
      int flat = tid + 256 * j;
      int row = flat >> 2, ch = (flat & 3) ^ ((row >> 1) & 3);
      gload_lds16(Bt + (size_t)(n0 + row) * Kdim + k0 + ch * 8,
                  (char*)Bs + wid * 1024 + j * 4096);
    }
    __syncthreads();

    short8 a[MT], b[NT];
    #pragma unroll
    for (int mt = 0; mt < MT; ++mt) {
      int row = wr * (BM / 2) + mt * 16 + lm;
      a[mt] = *(const short8*)&As[row * 32 + (lg ^ ((row >> 1) & 3)) * 8];
    }
    #pragma unroll
    for (int nt = 0; nt < NT; ++nt) {
      int row = wc * (BN / 2) + nt * 16 + lm;
      b[nt] = *(const short8*)&Bs[row * 32 + (lg ^ ((row >> 1) & 3)) * 8];
    }
    #pragma unroll
    for (int mt = 0; mt < MT; ++mt)
      #pragma unroll
      for (int nt = 0; nt < NT; ++nt)
        acc[mt][nt] = mfma16(a[mt], b[nt], acc[mt][nt]);
  }

  #pragma unroll
  for (int mt = 0; mt < MT; ++mt) {
    const int row0 = m0 + wr * (BM / 2) + mt * 16 + 4 * lg;
    #pragma unroll
    for (int nt = 0; nt < NT; ++nt) {
      const int col = n0 + wc * (BN / 2) + nt * 16 + lm;
      const float bv = bias[col];
      if (QKV && n0 >= 2048) {
        int hd = col - 2048;
        int bb = row0 >> 11, s = row0 & 2047;
        short4v pv;
        #pragma unroll
        for (int r = 0; r < 4; ++r) pv[r] = f2bf(acc[mt][nt][r] + bv);
        *(short4v*)&vt[((size_t)(bb * (NH * HD) + hd)) * SEQ + s] = pv;
      } else {
        #pragma unroll
        for (int r = 0; r < 4; ++r) {
          float v = acc[mt][nt][r] + bv;
          if (OUT_F32) ((float*)Cp)[(size_t)(row0 + r) * Ndim + col] = v;
          else         ((short*)Cp)[(size_t)(row0 + r) * Ndim + col] = f2bf(v);
        }
      }
    }
  }
}

// ---------- split-KV flash attention, swapped-QK^T form ----------
// Block = (id, bh), id in [0,144): (q-tile x of 64 rows, chunk c of 4 kv-tiles).
__global__ __launch_bounds__(256) void attn_kernel(
    const short* __restrict__ qkv, const short* __restrict__ vt,
    short* __restrict__ att, short* __restrict__ pO, float* __restrict__ pml)
{
  __shared__ short Ks[64 * 72];    // [kv][d], swizzled
  __shared__ short Vs[64 * 72];    // [d][kv], swizzled
  __shared__ short Ps[4 * 16 * 72];// per-wave P^T strip [q][kv], swizzled
  const int tid = threadIdx.x;
  const int wid = tid >> 6, lane = tid & 63, lg = lane >> 4, lm = lane & 15;

  int id = blockIdx.x, x, c;
  if (id < 4)        { x = id;                       c = 0;        }
  else if (id < 12)  { int t = id - 4;   x = 4  + (t >> 1); c = t & 1; }
  else if (id < 24)  { int t = id - 12;  x = 8  + t / 3;    c = t % 3; }
  else if (id < 40)  { int t = id - 24;  x = 12 + (t >> 2); c = t & 3; }
  else if (id < 60)  { int t = id - 40;  x = 16 + t / 5;    c = t % 5; }
  else if (id < 84)  { int t = id - 60;  x = 20 + t / 6;    c = t % 6; }
  else if (id < 112) { int t = id - 84;  x = 24 + t / 7;    c = t % 7; }
  else               { int t = id - 112; x = 28 + (t >> 3); c = t & 7; }
  const int nch = (x >> 2) + 1;
  const int tb = c * 4;
  const int te = min(tb + 4, x + 1);
  const int q0 = x * 64;
  const int bh = blockIdx.y, b = bh >> 4, h = bh & 15;
  const short* qp = qkv + (size_t)(b * SEQ) * NQKV + h * HD;
  const short* kp = qp + HID;
  const short* vp = vt + (size_t)bh * HD * SEQ;

  // Q fragments (B-operand), pre-scaled by log2(e)/sqrt(D); q-row = q0+wid*16+lm
  const float cl2 = 0.18033688011112042f;
  const int qrow_g = q0 + wid * 16 + lm;
  short8 qf[2];
  {
    const short* qrow = qp + (size_t)qrow_g * NQKV;
    #pragma unroll
    for (int kk = 0; kk < 2; ++kk) {
      short8 raw = *(const short8*)(qrow + kk * 32 + lg * 8);
      #pragma unroll
      for (int j = 0; j < 8; ++j) qf[kk][j] = f2bf(bf2f(raw[j]) * cl2);
    }
  }

  const int rstage = tid >> 3, c8 = (tid & 7) * 8;
  short8 kreg[2], vreg[2];
  #pragma unroll
  for (int i = 0; i < 2; ++i) {
    kreg[i] = *(const short8*)(kp + (size_t)(tb * 64 + rstage + 32 * i) * NQKV + c8);
    vreg[i] = *(const short8*)(vp + (size_t)(rstage + 32 * i) * SEQ + tb * 64 + c8);
  }

  short* psw = Ps + wid * 16 * 72;
  float mrow = -3e38f, lrow = 0.f;
  floatx4 o[4];   // O^T: o[nt][r] = O[d = nt*16+4lg+r][q = lm]
  #pragma unroll
  for (int nt = 0; nt < 4; ++nt) o[nt] = floatx4{0.f, 0.f, 0.f, 0.f};

  for (int t = tb; t < te; ++t) {
    __syncthreads();
    #pragma unroll
    for (int i = 0; i < 2; ++i) {
      lds_w8(Ks, rstage + 32 * i, c8, kreg[i]);
      lds_w8(Vs, rstage + 32 * i, c8, vreg[i]);
    }
    __syncthreads();
    if (t + 1 < te) {
      const int kv1 = (t + 1) * 64;
      #pragma unroll
      for (int i = 0; i < 2; ++i) {
        kreg[i] = *(const short8*)(kp + (size_t)(kv1 + rstage + 32 * i) * NQKV + c8);
        vreg[i] = *(const short8*)(vp + (size_t)(rstage + 32 * i) * SEQ + kv1 + c8);
      }
    }

    // S^T = K Q^T : s[nt] rows = kv (nt*16+4lg+r), col = q (lm)
    floatx4 s[4];
    #pragma unroll
    for (int nt = 0; nt < 4; ++nt) s[nt] = floatx4{0.f, 0.f, 0.f, 0.f};
    #pragma unroll
    for (int kk = 0; kk < 2; ++kk)
      #pragma unroll
      for (int nt = 0; nt < 4; ++nt)
        s[nt] = mfma16(lds_r8(Ks, nt * 16 + lm, kk * 32 + lg * 8), qf[kk], s[nt]);

    // mask (diagonal tile only) + in-lane max over this lane's 16 scores
    float pmax = -3e38f;
    if (t == x) {
      #pragma unroll
      for (int nt = 0; nt < 4; ++nt)
        #pragma unroll
        for (int r = 0; r < 4; ++r) {
          int kv = t * 64 + nt * 16 + 4 * lg + r;
          float val = (kv > qrow_g) ? -3e38f : s[nt][r];
          s[nt][r] = val; pmax = fmaxf(pmax, val);
        }
    } else {
      #pragma unroll
      for (int nt = 0; nt < 4; ++nt)
        #pragma unroll
        for (int r = 0; r < 4; ++r) pmax = fmaxf(pmax, s[nt][r]);
    }
    // cross-lg reduce (lanes lm, lm+16, lm+32, lm+48 share q-row)
    pmax = fmaxf(pmax, __shfl_xor(pmax, 16));
    pmax = fmaxf(pmax, __shfl_xor(pmax, 32));

    // defer-max (T13): skip rescale when max growth small (log2 domain)
    bool skip = __all(pmax <= mrow + 11.54f);
    float mnew = skip ? mrow : fmaxf(mrow, pmax);
    float corr = exp2fast(mrow - mnew);
    mrow = mnew;

    float psum = 0.f;
    #pragma unroll
    for (int nt = 0; nt < 4; ++nt)
      #pragma unroll
      for (int r = 0; r < 4; ++r) {
        float e = exp2fast(s[nt][r] - mnew);
        s[nt][r] = e; psum += e;
      }
    psum += __shfl_xor(psum, 16);
    psum += __shfl_xor(psum, 32);
    lrow = lrow * corr + psum;
    if (!skip) {
      #pragma unroll
      for (int nt = 0; nt < 4; ++nt)
        #pragma unroll
        for (int r = 0; r < 4; ++r) o[nt][r] *= corr;
    }

    // P^T -> per-wave LDS strip [q=lm][kv], vectorized b64 writes
    #pragma unroll
    for (int nt = 0; nt < 4; ++nt) {
      short4v pv;
      #pragma unroll
      for (int r = 0; r < 4; ++r) pv[r] = f2bf(s[nt][r]);
      lds_w4(psw, lm, nt * 16 + 4 * lg, pv);
    }

    // O^T += V^T P^T : A = V^T frag (contiguous), B = P^T frag (contiguous!)
    #pragma unroll
    for (int kk = 0; kk < 2; ++kk) {
      short8 pf = lds_r8(psw, lm, kk * 32 + lg * 8);
      #pragma unroll
      for (int nt = 0; nt < 4; ++nt)
        o[nt] = mfma16(lds_r8(Vs, nt * 16 + lm, kk * 32 + lg * 8), pf, o[nt]);
    }
  }

  if (nch == 1) {
    const float linv = 1.0f / lrow;
    #pragma unroll
    for (int nt = 0; nt < 4; ++nt) {
      short4v ov;
      #pragma unroll
      for (int r = 0; r < 4; ++r) ov[r] = f2bf(o[nt][r] * linv);
      *(short4v*)&att[((size_t)(b * SEQ + qrow_g)) * HID + h * HD + nt * 16 + 4 * lg] = ov;
    }
  } else {
    const int g = x >> 2;
    const int slot = bh * 140 + (2 * g * g + 2 * g - 4 + (x & 3) * (g + 1)) + c;
    short* po = pO + (size_t)slot * 4096;
    const int ql = wid * 16 + lm;
    #pragma unroll
    for (int nt = 0; nt < 4; ++nt) {
      short4v ov;
      #pragma unroll
      for (int r = 0; r < 4; ++r) ov[r] = f2bf(o[nt][r]);
      *(short4v*)&po[ql * 64 + nt * 16 + 4 * lg] = ov;
    }
    if (lane < 16) {
      pml[slot * 128 + ql] = mrow;
      pml[slot * 128 + 64 + ql] = lrow;
    }
  }
}

// ---------- combine partials: grid (28, 32) ----------
__global__ __launch_bounds__(256) void combine_kernel(
    const short* __restrict__ pO, const float* __restrict__ pml,
    short* __restrict__ att)
{
  const int x = 4 + blockIdx.x;
  const int bh = blockIdx.y, b = bh >> 4, h = bh & 15;
  const int g = x >> 2;
  const int nch = g + 1;                  // 2..8
  const int tid = threadIdx.x;
  const int row = tid >> 2, d0 = (tid & 3) * 16;
  const int base_slot = bh * 140 + (2 * g * g + 2 * g - 4 + (x & 3) * (g + 1));

  float mv[8], lv[8], M = -3e38f;
  for (int cc = 0; cc < nch; ++cc) {
    mv[cc] = pml[(base_slot + cc) * 128 + row];
    lv[cc] = pml[(base_slot + cc) * 128 + 64 + row];
    M = fmaxf(M, mv[cc]);
  }
  float L = 0.f, w[8];
  for (int cc = 0; cc < nch; ++cc) {
    w[cc] = exp2fast(mv[cc] - M);
    L += lv[cc] * w[cc];
  }
  const float inv = 1.0f / L;

  float acc[16];
  #pragma unroll
  for (int j = 0; j < 16; ++j) acc[j] = 0.f;
  for (int cc = 0; cc < nch; ++cc) {
    const short* po = pO + (size_t)(base_slot + cc) * 4096 + row * 64 + d0;
    short8 v0 = *(const short8*)po, v1 = *(const short8*)(po + 8);
    #pragma unroll
    for (int j = 0; j < 8; ++j) {
      acc[j]     += bf2f(v0[j]) * w[cc];
      acc[j + 8] += bf2f(v1[j]) * w[cc];
    }
  }
  short8 o0, o1;
  #pragma unroll
  for (int j = 0; j < 8; ++j) {
    o0[j] = f2bf(acc[j] * inv);
    o1[j] = f2bf(acc[j + 8] * inv);
  }
  short* dst = att + ((size_t)(b * SEQ + x * 64 + row)) * HID + h * HD + d0;
  *(short8*)dst = o0;
  *(short8*)(dst + 8) = o1;
}

extern "C" void kernel_launch(void* const* d_in, const int* in_sizes, int n_in,
                              void* d_out, int out_size, void* d_ws, size_t ws_size,
                              hipStream_t stream) {
  (void)in_sizes; (void)n_in; (void)out_size; (void)ws_size;
  const float* x    = (const float*)d_in[0];
  const float* Wq   = (const float*)d_in[1];
  const float* bq   = (const float*)d_in[2];
  const float* Wk   = (const float*)d_in[3];
  const float* bk   = (const float*)d_in[4];
  const float* Wv   = (const float*)d_in[5];
  const float* bv   = (const float*)d_in[6];
  const float* Wmix = (const float*)d_in[7];
  const float* bmix = (const float*)d_in[8];
  float* out = (float*)d_out;

  char* w = (char*)d_ws;
  short* xb      = (short*)w; w += (size_t)8 << 20;
  short* Wt      = (short*)w; w += (size_t)6 << 20;
  short* Wmixt   = (short*)w; w += (size_t)2 << 20;
  float* biascat = (float*)w; w += (size_t)64 << 10;
  short* qkvb    = (short*)w; w += (size_t)24 << 20;
  short* vtb     = (short*)w; w += (size_t)8 << 20;
  short* ab      = (short*)w; w += (size_t)8 << 20;
  short* pO      = (short*)w; w += (size_t)140 * 32 * 4096 * 2;
  float* pml     = (float*)w;

  hipLaunchKernelGGL(convx_kernel, dim3(2048), dim3(256), 0, stream, x, xb);
  hipLaunchKernelGGL(transw_kernel, dim3(16, 16, 4), dim3(256), 0, stream,
                     Wq, Wk, Wv, Wmix, Wt, Wmixt);
  hipMemcpyAsync(biascat,        bq, 1024 * sizeof(float), hipMemcpyDeviceToDevice, stream);
  hipMemcpyAsync(biascat + 1024, bk, 1024 * sizeof(float), hipMemcpyDeviceToDevice, stream);
  hipMemcpyAsync(biascat + 2048, bv, 1024 * sizeof(float), hipMemcpyDeviceToDevice, stream);

  hipLaunchKernelGGL((gemm_kernel<128, 128, false, true>), dim3(NQKV / 128, M_ROWS / 128),
                     dim3(256), 0, stream, xb, Wt, biascat, (void*)qkvb, vtb, NQKV, DIN);

  hipLaunchKernelGGL(attn_kernel, dim3(144, BS * NH), dim3(256), 0, stream,
                     qkvb, vtb, ab, pO, pml);
  hipLaunchKernelGGL(combine_kernel, dim3(28, BS * NH), dim3(256), 0, stream,
                     pO, pml, ab);

  hipLaunchKernelGGL((gemm_kernel<64, 128, true, false>), dim3(HID / 128, M_ROWS / 64),
                     dim3(256), 0, stream, ab, Wmixt, bmix, (void*)out, (short*)nullptr,
                     HID, DIN);
}

// Round 5
// 133.044 us; speedup vs baseline: 2.4267x; 1.1336x over previous
//
#include <hip/hip_runtime.h>
#include <hip/hip_bf16.h>

#define BS 2
#define SEQ 2048
#define DIN 1024
#define HID 1024
#define NH 16
#define HD 64
#define M_ROWS (BS*SEQ)
#define NQKV 3072

typedef __attribute__((ext_vector_type(8))) short short8;
typedef __attribute__((ext_vector_type(4))) short short4v;
typedef __attribute__((ext_vector_type(8))) __bf16 bf16x8;
typedef __attribute__((ext_vector_type(4))) float floatx4;

// native cast -> v_cvt_pk_bf16_f32 when paired (RNE)
__device__ __forceinline__ short f2bf(float f) {
  return __builtin_bit_cast(short, (__bf16)f);
}
__device__ __forceinline__ float bf2f(short s) {
  return __uint_as_float(((unsigned)(unsigned short)s) << 16);
}

__device__ __forceinline__ floatx4 mfma16(short8 a, short8 b, floatx4 c) {
  return __builtin_amdgcn_mfma_f32_16x16x32_bf16(
      __builtin_bit_cast(bf16x8, a), __builtin_bit_cast(bf16x8, b), c, 0, 0, 0);
}

__device__ __forceinline__ float exp2fast(float x) {
#if __has_builtin(__builtin_amdgcn_exp2f)
  return __builtin_amdgcn_exp2f(x);
#else
  return exp2f(x);
#endif
}

__device__ __forceinline__ void gload_lds16(const void* g, void* l) {
  __builtin_amdgcn_global_load_lds(
      (const __attribute__((address_space(1))) unsigned int*)g,
      (__attribute__((address_space(3))) unsigned int*)l, 16, 0, 0);
}

// Linear LDS helpers, row stride 72 shorts (144B = 4-bank shift/row; 2-way max)
__device__ __forceinline__ void lds_w8(short* base, int row, int colsh, short8 v) {
  *(short8*)((char*)base + row * 144 + colsh * 2) = v;
}
__device__ __forceinline__ void lds_w4(short* base, int row, int colsh, short4v v) {
  *(short4v*)((char*)base + row * 144 + colsh * 2) = v;
}
__device__ __forceinline__ short8 lds_r8(const short* base, int row, int colsh) {
  return *(const short8*)((const char*)base + row * 144 + colsh * 2);
}

// ---------- pre-pass: x fp32 -> bf16 ----------
__global__ __launch_bounds__(256) void convx_kernel(const float* __restrict__ x,
                                                    short* __restrict__ xb) {
  int gid = blockIdx.x * 256 + threadIdx.x;
  const float4* x4 = (const float4*)x;
  float4 v0 = x4[2 * gid], v1 = x4[2 * gid + 1];
  short8 o;
  o[0] = f2bf(v0.x); o[1] = f2bf(v0.y); o[2] = f2bf(v0.z); o[3] = f2bf(v0.w);
  o[4] = f2bf(v1.x); o[5] = f2bf(v1.y); o[6] = f2bf(v1.z); o[7] = f2bf(v1.w);
  *(short8*)&xb[(size_t)gid * 8] = o;
}

// ---------- pre-pass: W [K][N] fp32 -> Wt [N][K] bf16 ----------
__global__ __launch_bounds__(256) void transw_kernel(
    const float* __restrict__ Wq, const float* __restrict__ Wk,
    const float* __restrict__ Wv, const float* __restrict__ Wmix,
    short* __restrict__ Wt, short* __restrict__ Wmixt)
{
  __shared__ float Ws[64][65];
  const float* src; short* dst;
  switch (blockIdx.z) {
    case 0:  src = Wq;   dst = Wt;                 break;
    case 1:  src = Wk;   dst = Wt + (1u << 20);    break;
    case 2:  src = Wv;   dst = Wt + (2u << 20);    break;
    default: src = Wmix; dst = Wmixt;              break;
  }
  const int n0 = blockIdx.x * 64, k0 = blockIdx.y * 64;
  const int c = threadIdx.x & 63, r0 = threadIdx.x >> 6;
  #pragma unroll
  for (int i = 0; i < 16; ++i) {
    int rr = r0 + 4 * i;
    Ws[rr][c] = src[(size_t)(k0 + rr) * DIN + n0 + c];
  }
  __syncthreads();
  #pragma unroll
  for (int i = 0; i < 16; ++i) {
    int cc = r0 + 4 * i;
    dst[(size_t)(n0 + cc) * DIN + k0 + c] = f2bf(Ws[c][cc]);
  }
}

// ---------- GEMM: C[M][N] = A[M][K]bf16 @ Bt[N][K]bf16^T + bias ----------
template<int BM, int BN, bool OUT_F32, bool QKV>
__global__ __launch_bounds__(256) void gemm_kernel(
    const short* __restrict__ A, const short* __restrict__ Bt,
    const float* __restrict__ bias, void* __restrict__ Cp,
    short* __restrict__ vt, int Ndim, int Kdim)
{
  constexpr int MT = BM / 32, NT = BN / 32;
  __shared__ short As[BM * 32];
  __shared__ short Bs[BN * 32];
  const int tid = threadIdx.x;
  const int wid = tid >> 6, lane = tid & 63, lg = lane >> 4, lm = lane & 15;
  const int wr = wid >> 1, wc = wid & 1;
  const int m0 = blockIdx.y * BM, n0 = blockIdx.x * BN;

  floatx4 acc[MT][NT];
  #pragma unroll
  for (int i = 0; i < MT; ++i)
    #pragma unroll
    for (int j = 0; j < NT; ++j) acc[i][j] = floatx4{0.f, 0.f, 0.f, 0.f};

  for (int k0 = 0; k0 < Kdim; k0 += 32) {
    __syncthreads();
    #pragma unroll
    for (int j = 0; j < BM / 64; ++j) {
      int flat = tid + 256 * j;
      int row = flat >> 2, ch = (flat & 3) ^ ((row >> 1) & 3);
      gload_lds16(A + (size_t)(m0 + row) * Kdim + k0 + ch * 8,
                  (char*)As + wid * 1024 + j * 4096);
    }
    #pragma unroll
    for (int j = 0; j < BN / 64; ++j) {
      int flat = tid + 256 * j;
      int row = flat >> 2, ch = (flat & 3) ^ ((row >> 1) & 3);
      gload_lds16(Bt + (size_t)(n0 + row) * Kdim + k0 + ch * 8,
                  (char*)Bs + wid * 1024 + j * 4096);
    }
    __syncthreads();

    short8 a[MT], b[NT];
    #pragma unroll
    for (int mt = 0; mt < MT; ++mt) {
      int row = wr * (BM / 2) + mt * 16 + lm;
      a[mt] = *(const short8*)&As[row * 32 + (lg ^ ((row >> 1) & 3)) * 8];
    }
    #pragma unroll
    for (int nt = 0; nt < NT; ++nt) {
      int row = wc * (BN / 2) + nt * 16 + lm;
      b[nt] = *(const short8*)&Bs[row * 32 + (lg ^ ((row >> 1) & 3)) * 8];
    }
    #pragma unroll
    for (int mt = 0; mt < MT; ++mt)
      #pragma unroll
      for (int nt = 0; nt < NT; ++nt)
        acc[mt][nt] = mfma16(a[mt], b[nt], acc[mt][nt]);
  }

  #pragma unroll
  for (int mt = 0; mt < MT; ++mt) {
    const int row0 = m0 + wr * (BM / 2) + mt * 16 + 4 * lg;
    #pragma unroll
    for (int nt = 0; nt < NT; ++nt) {
      const int col = n0 + wc * (BN / 2) + nt * 16 + lm;
      const float bv = bias[col];
      if (QKV && n0 >= 2048) {
        int hd = col - 2048;
        int bb = row0 >> 11, s = row0 & 2047;
        short4v pv;
        #pragma unroll
        for (int r = 0; r < 4; ++r) pv[r] = f2bf(acc[mt][nt][r] + bv);
        *(short4v*)&vt[((size_t)(bb * (NH * HD) + hd)) * SEQ + s] = pv;
      } else {
        #pragma unroll
        for (int r = 0; r < 4; ++r) {
          float v = acc[mt][nt][r] + bv;
          if (OUT_F32) ((float*)Cp)[(size_t)(row0 + r) * Ndim + col] = v;
          else         ((short*)Cp)[(size_t)(row0 + r) * Ndim + col] = f2bf(v);
        }
      }
    }
  }
}

// ---------- split-KV flash attention, swapped-QK^T form ----------
// Block = (id, bh), id in [0,144): (q-tile x of 64 rows, chunk c of 4 kv-tiles).
__global__ __launch_bounds__(256) void attn_kernel(
    const short* __restrict__ qkv, const short* __restrict__ vt,
    short* __restrict__ att, short* __restrict__ pO, float* __restrict__ pml)
{
  __shared__ short Ks[64 * 72];    // [kv][d]
  __shared__ short Vs[64 * 72];    // [d][kv]
  __shared__ short Ps[4 * 16 * 72];// per-wave P^T strip [q][kv]
  const int tid = threadIdx.x;
  const int wid = tid >> 6, lane = tid & 63, lg = lane >> 4, lm = lane & 15;

  int id = blockIdx.x, x, c;
  if (id < 4)        { x = id;                       c = 0;        }
  else if (id < 12)  { int t = id - 4;   x = 4  + (t >> 1); c = t & 1; }
  else if (id < 24)  { int t = id - 12;  x = 8  + t / 3;    c = t % 3; }
  else if (id < 40)  { int t = id - 24;  x = 12 + (t >> 2); c = t & 3; }
  else if (id < 60)  { int t = id - 40;  x = 16 + t / 5;    c = t % 5; }
  else if (id < 84)  { int t = id - 60;  x = 20 + t / 6;    c = t % 6; }
  else if (id < 112) { int t = id - 84;  x = 24 + t / 7;    c = t % 7; }
  else               { int t = id - 112; x = 28 + (t >> 3); c = t & 7; }
  const int nch = (x >> 2) + 1;
  const int tb = c * 4;
  const int te = min(tb + 4, x + 1);
  const int q0 = x * 64;
  const int bh = blockIdx.y, b = bh >> 4, h = bh & 15;
  const short* qp = qkv + (size_t)(b * SEQ) * NQKV + h * HD;
  const short* kp = qp + HID;
  const short* vp = vt + (size_t)bh * HD * SEQ;

  // Q fragments (B-operand), pre-scaled by log2(e)/sqrt(D); q-row = q0+wid*16+lm
  const float cl2 = 0.18033688011112042f;
  const int qrow_g = q0 + wid * 16 + lm;
  short8 qf[2];
  {
    const short* qrow = qp + (size_t)qrow_g * NQKV;
    #pragma unroll
    for (int kk = 0; kk < 2; ++kk) {
      short8 raw = *(const short8*)(qrow + kk * 32 + lg * 8);
      #pragma unroll
      for (int j = 0; j < 8; ++j) qf[kk][j] = f2bf(bf2f(raw[j]) * cl2);
    }
  }

  const int rstage = tid >> 3, c8 = (tid & 7) * 8;
  short8 kreg[2], vreg[2];
  #pragma unroll
  for (int i = 0; i < 2; ++i) {
    kreg[i] = *(const short8*)(kp + (size_t)(tb * 64 + rstage + 32 * i) * NQKV + c8);
    vreg[i] = *(const short8*)(vp + (size_t)(rstage + 32 * i) * SEQ + tb * 64 + c8);
  }

  short* psw = Ps + wid * 16 * 72;
  float mrow = -3e38f, lrow = 0.f;
  floatx4 o[4];   // O^T: o[nt][r] = O[d = nt*16+4lg+r][q = lm]
  #pragma unroll
  for (int nt = 0; nt < 4; ++nt) o[nt] = floatx4{0.f, 0.f, 0.f, 0.f};

  for (int t = tb; t < te; ++t) {
    __syncthreads();
    #pragma unroll
    for (int i = 0; i < 2; ++i) {
      lds_w8(Ks, rstage + 32 * i, c8, kreg[i]);
      lds_w8(Vs, rstage + 32 * i, c8, vreg[i]);
    }
    __syncthreads();
    if (t + 1 < te) {
      const int kv1 = (t + 1) * 64;
      #pragma unroll
      for (int i = 0; i < 2; ++i) {
        kreg[i] = *(const short8*)(kp + (size_t)(kv1 + rstage + 32 * i) * NQKV + c8);
        vreg[i] = *(const short8*)(vp + (size_t)(rstage + 32 * i) * SEQ + kv1 + c8);
      }
    }

    // S^T = K Q^T : s[nt] rows = kv (nt*16+4lg+r), col = q (lm)
    floatx4 s[4];
    #pragma unroll
    for (int nt = 0; nt < 4; ++nt) s[nt] = floatx4{0.f, 0.f, 0.f, 0.f};
    __builtin_amdgcn_s_setprio(1);
    #pragma unroll
    for (int kk = 0; kk < 2; ++kk)
      #pragma unroll
      for (int nt = 0; nt < 4; ++nt)
        s[nt] = mfma16(lds_r8(Ks, nt * 16 + lm, kk * 32 + lg * 8), qf[kk], s[nt]);
    __builtin_amdgcn_s_setprio(0);

    // mask (diagonal tile only) + in-lane max over this lane's 16 scores
    float pmax = -3e38f;
    if (t == x) {
      #pragma unroll
      for (int nt = 0; nt < 4; ++nt)
        #pragma unroll
        for (int r = 0; r < 4; ++r) {
          int kv = t * 64 + nt * 16 + 4 * lg + r;
          float val = (kv > qrow_g) ? -3e38f : s[nt][r];
          s[nt][r] = val; pmax = fmaxf(pmax, val);
        }
    } else {
      #pragma unroll
      for (int nt = 0; nt < 4; ++nt)
        #pragma unroll
        for (int r = 0; r < 4; ++r) pmax = fmaxf(pmax, s[nt][r]);
    }
    // cross-lg reduce (lanes lm, lm+16, lm+32, lm+48 share q-row)
    pmax = fmaxf(pmax, __shfl_xor(pmax, 16));
    pmax = fmaxf(pmax, __shfl_xor(pmax, 32));

    // defer-max (T13): skip rescale when max growth small (log2 domain)
    bool skip = __all(pmax <= mrow + 11.54f);
    float mnew = skip ? mrow : fmaxf(mrow, pmax);
    float corr = exp2fast(mrow - mnew);
    mrow = mnew;

    float psum = 0.f;
    #pragma unroll
    for (int nt = 0; nt < 4; ++nt)
      #pragma unroll
      for (int r = 0; r < 4; ++r) {
        float e = exp2fast(s[nt][r] - mnew);
        s[nt][r] = e; psum += e;
      }
    psum += __shfl_xor(psum, 16);
    psum += __shfl_xor(psum, 32);
    lrow = lrow * corr + psum;
    if (!skip) {
      #pragma unroll
      for (int nt = 0; nt < 4; ++nt)
        #pragma unroll
        for (int r = 0; r < 4; ++r) o[nt][r] *= corr;
    }

    // P^T -> per-wave LDS strip [q=lm][kv], vectorized b64 writes
    #pragma unroll
    for (int nt = 0; nt < 4; ++nt) {
      short4v pv;
      #pragma unroll
      for (int r = 0; r < 4; ++r) pv[r] = f2bf(s[nt][r]);
      lds_w4(psw, lm, nt * 16 + 4 * lg, pv);
    }

    // O^T += V^T P^T : A = V^T frag (contiguous), B = P^T frag (contiguous)
    #pragma unroll
    for (int kk = 0; kk < 2; ++kk) {
      short8 pf = lds_r8(psw, lm, kk * 32 + lg * 8);
      __builtin_amdgcn_s_setprio(1);
      #pragma unroll
      for (int nt = 0; nt < 4; ++nt)
        o[nt] = mfma16(lds_r8(Vs, nt * 16 + lm, kk * 32 + lg * 8), pf, o[nt]);
      __builtin_amdgcn_s_setprio(0);
    }
  }

  if (nch == 1) {
    const float linv = 1.0f / lrow;
    #pragma unroll
    for (int nt = 0; nt < 4; ++nt) {
      short4v ov;
      #pragma unroll
      for (int r = 0; r < 4; ++r) ov[r] = f2bf(o[nt][r] * linv);
      *(short4v*)&att[((size_t)(b * SEQ + qrow_g)) * HID + h * HD + nt * 16 + 4 * lg] = ov;
    }
  } else {
    const int g = x >> 2;
    const int slot = bh * 140 + (2 * g * g + 2 * g - 4 + (x & 3) * (g + 1)) + c;
    short* po = pO + (size_t)slot * 4096;
    const int ql = wid * 16 + lm;
    #pragma unroll
    for (int nt = 0; nt < 4; ++nt) {
      short4v ov;
      #pragma unroll
      for (int r = 0; r < 4; ++r) ov[r] = f2bf(o[nt][r]);
      *(short4v*)&po[ql * 64 + nt * 16 + 4 * lg] = ov;
    }
    if (lane < 16) {
      pml[slot * 128 + ql] = mrow;
      pml[slot * 128 + 64 + ql] = lrow;
    }
  }
}

// ---------- combine partials: grid (28, 32) ----------
__global__ __launch_bounds__(256) void combine_kernel(
    const short* __restrict__ pO, const float* __restrict__ pml,
    short* __restrict__ att)
{
  const int x = 4 + blockIdx.x;
  const int bh = blockIdx.y, b = bh >> 4, h = bh & 15;
  const int g = x >> 2;
  const int nch = g + 1;                  // 2..8
  const int tid = threadIdx.x;
  const int row = tid >> 2, d0 = (tid & 3) * 16;
  const int base_slot = bh * 140 + (2 * g * g + 2 * g - 4 + (x & 3) * (g + 1));

  float mv[8], lv[8], M = -3e38f;
  for (int cc = 0; cc < nch; ++cc) {
    mv[cc] = pml[(base_slot + cc) * 128 + row];
    lv[cc] = pml[(base_slot + cc) * 128 + 64 + row];
    M = fmaxf(M, mv[cc]);
  }
  float L = 0.f, w[8];
  for (int cc = 0; cc < nch; ++cc) {
    w[cc] = exp2fast(mv[cc] - M);
    L += lv[cc] * w[cc];
  }
  const float inv = 1.0f / L;

  float acc[16];
  #pragma unroll
  for (int j = 0; j < 16; ++j) acc[j] = 0.f;
  for (int cc = 0; cc < nch; ++cc) {
    const short* po = pO + (size_t)(base_slot + cc) * 4096 + row * 64 + d0;
    short8 v0 = *(const short8*)po, v1 = *(const short8*)(po + 8);
    #pragma unroll
    for (int j = 0; j < 8; ++j) {
      acc[j]     += bf2f(v0[j]) * w[cc];
      acc[j + 8] += bf2f(v1[j]) * w[cc];
    }
  }
  short8 o0, o1;
  #pragma unroll
  for (int j = 0; j < 8; ++j) {
    o0[j] = f2bf(acc[j] * inv);
    o1[j] = f2bf(acc[j + 8] * inv);
  }
  short* dst = att + ((size_t)(b * SEQ + x * 64 + row)) * HID + h * HD + d0;
  *(short8*)dst = o0;
  *(short8*)(dst + 8) = o1;
}

extern "C" void kernel_launch(void* const* d_in, const int* in_sizes, int n_in,
                              void* d_out, int out_size, void* d_ws, size_t ws_size,
                              hipStream_t stream) {
  (void)in_sizes; (void)n_in; (void)out_size; (void)ws_size;
  const float* x    = (const float*)d_in[0];
  const float* Wq   = (const float*)d_in[1];
  const float* bq   = (const float*)d_in[2];
  const float* Wk   = (const float*)d_in[3];
  const float* bk   = (const float*)d_in[4];
  const float* Wv   = (const float*)d_in[5];
  const float* bv   = (const float*)d_in[6];
  const float* Wmix = (const float*)d_in[7];
  const float* bmix = (const float*)d_in[8];
  float* out = (float*)d_out;

  char* w = (char*)d_ws;
  short* xb      = (short*)w; w += (size_t)8 << 20;
  short* Wt      = (short*)w; w += (size_t)6 << 20;
  short* Wmixt   = (short*)w; w += (size_t)2 << 20;
  float* biascat = (float*)w; w += (size_t)64 << 10;
  short* qkvb    = (short*)w; w += (size_t)24 << 20;
  short* vtb     = (short*)w; w += (size_t)8 << 20;
  short* ab      = (short*)w; w += (size_t)8 << 20;
  short* pO      = (short*)w; w += (size_t)140 * 32 * 4096 * 2;
  float* pml     = (float*)w;

  hipLaunchKernelGGL(convx_kernel, dim3(2048), dim3(256), 0, stream, x, xb);
  hipLaunchKernelGGL(transw_kernel, dim3(16, 16, 4), dim3(256), 0, stream,
                     Wq, Wk, Wv, Wmix, Wt, Wmixt);
  hipMemcpyAsync(biascat,        bq, 1024 * sizeof(float), hipMemcpyDeviceToDevice, stream);
  hipMemcpyAsync(biascat + 1024, bk, 1024 * sizeof(float), hipMemcpyDeviceToDevice, stream);
  hipMemcpyAsync(biascat + 2048, bv, 1024 * sizeof(float), hipMemcpyDeviceToDevice, stream);

  hipLaunchKernelGGL((gemm_kernel<128, 128, false, true>), dim3(NQKV / 128, M_ROWS / 128),
                     dim3(256), 0, stream, xb, Wt, biascat, (void*)qkvb, vtb, NQKV, DIN);

  hipLaunchKernelGGL(attn_kernel, dim3(144, BS * NH), dim3(256), 0, stream,
                     qkvb, vtb, ab, pO, pml);
  hipLaunchKernelGGL(combine_kernel, dim3(28, BS * NH), dim3(256), 0, stream,
                     pO, pml, ab);

  hipLaunchKernelGGL((gemm_kernel<64, 128, true, false>), dim3(HID / 128, M_ROWS / 64),
                     dim3(256), 0, stream, ab, Wmixt, bmix, (void*)out, (short*)nullptr,
                     HID, DIN);
}